// Round 9
// baseline (339.888 us; speedup 1.0000x reference)
//
#include <hip/hip_runtime.h>

// QINCoStep — bs=2048, d=128, K=256, h=256, fp32 in/out.
// Round 9 (= R8 design with fixed ws layout; R8's H1bf slot was half-sized and
// overlapped F/W2f0, corrupting blk0 weights).
//   k_prep1  : weight transposes + bf16 A-fragment pack
//   k_prep2  : z0/z0bf/H1bf (k-role) + u/ubf/U1bf (b-role), one launch
//   k_dist   : bf16-MFMA approx dist + per-(b,half) candidate select (no atomics)
//   k_final2 : per-b exact f32 recompute of <=16 cands, pick, write outputs
//
// ws layout (floats):
//   0 WzT 16384 | 16384 WxT 16384 | 32768 W1T0 32768 | 65536 W2T0 32768
//   98304 W1T1 32768 | 131072 W2T1 32768 | 163840 z0 32768 | 196608 u 262144
//   458752 z0bf (32768 us = 16384 fl)   -> ends 475136
//   475136 ubf  (262144 us = 131072 fl) -> ends 606208
//   606208 U1bf (524288 us = 262144 fl) -> ends 868352
//   868352 H1bf (65536 us = 32768 fl)   -> ends 901120
//   901120 F (12288 uint4 = 49152 fl)   -> ends 950272
//   950272 cand (32768 int)             -> ends 983040
//   983040 cnt (4096 int)               -> ends 987136

typedef short bf8_t __attribute__((ext_vector_type(8)));
typedef float f32x16 __attribute__((ext_vector_type(16)));

__device__ inline unsigned short f2bh(float x) {   // RNE f32->bf16 (prep only)
    unsigned u = __float_as_uint(x);
    u += 0x7fffu + ((u >> 16) & 1u);
    return (unsigned short)(u >> 16);
}
__device__ inline float bh2f(unsigned short h) {
    return __uint_as_float(((unsigned)h) << 16);
}
__device__ inline f32x16 mfma_bf(uint4 a, uint4 b, f32x16 c) {
    bf8_t av = __builtin_bit_cast(bf8_t, a);
    bf8_t bv = __builtin_bit_cast(bf8_t, b);
    return __builtin_amdgcn_mfma_f32_32x32x16_bf16(av, bv, c, 0, 0, 0);
}
// truncation pack: hi16(x) low half, hi16(y) high half — 1 v_perm_b32
__device__ inline unsigned packhi(float x, float y) {
    return __builtin_amdgcn_perm(__float_as_uint(y), __float_as_uint(x), 0x07060302u);
}
// (bf16pair hv) + (bf16pair uv) -> relu -> trunc bf16pair
__device__ inline unsigned addrelu2t(unsigned hv, unsigned uv) {
    float a0 = __uint_as_float(hv << 16) + __uint_as_float(uv << 16);
    float a1 = __uint_as_float(hv & 0xFFFF0000u) + __uint_as_float(uv & 0xFFFF0000u);
    return packhi(fmaxf(a0, 0.f), fmaxf(a1, 0.f));
}

#define DELTA 6.5f

// ---------------- prep1: transposes + frag pack ----------------
__global__ __launch_bounds__(256) void k_prep1(
    const float* __restrict__ Wc,
    const float* __restrict__ W1a, const float* __restrict__ W2a,
    const float* __restrict__ W1b, const float* __restrict__ W2b,
    float* __restrict__ WzT, float* __restrict__ WxT,
    float* __restrict__ W1Ta, float* __restrict__ W2Ta,
    float* __restrict__ W1Tb, float* __restrict__ W2Tb,
    uint4* __restrict__ F)
{
    int g = blockIdx.x * 256 + threadIdx.x;
    if (g < 16384) {
        int j = g >> 7, d = g & 127;
        WzT[g] = Wc[d * 256 + j];
    } else if (g < 32768) {
        int e = g - 16384; int j = e >> 7, d = e & 127;
        WxT[e] = Wc[d * 256 + 128 + j];
    } else if (g < 65536) {
        int e = g - 32768; int d = e >> 8, h = e & 255;
        W1Ta[e] = W1a[h * 128 + d];
    } else if (g < 98304) {
        int e = g - 65536; int h = e >> 7, i = e & 127;
        W2Ta[e] = W2a[i * 256 + h];
    } else if (g < 131072) {
        int e = g - 98304; int d = e >> 8, h = e & 255;
        W1Tb[e] = W1b[h * 128 + d];
    } else if (g < 163840) {
        int e = g - 131072; int h = e >> 7, i = e & 127;
        W2Tb[e] = W2b[i * 256 + h];
    } else if (g < 176128) {   // 12288 frag-lane slots (RNE)
        int idx = g - 163840;
        int mat = idx >> 12, fp = idx & 4095;
        int tile = fp >> 6, lane = fp & 63;
        const float* src;
        if (mat == 1) {            // W1_1: [256][128], 8mt x 8kt
            int mt = tile >> 3, kt = tile & 7;
            src = W1b + (32 * mt + (lane & 31)) * 128 + 16 * kt + 8 * (lane >> 5);
        } else {                   // W2-type: [128][256], 4mt x 16kt
            const float* W = (mat == 0) ? W2a : W2b;
            int mt = tile >> 4, kt = tile & 15;
            src = W + (32 * mt + (lane & 31)) * 256 + 16 * kt + 8 * (lane >> 5);
        }
        unsigned short hs[8];
#pragma unroll
        for (int j = 0; j < 8; ++j) hs[j] = f2bh(src[j]);
        uint4 hv;
        hv.x = (unsigned)hs[0] | ((unsigned)hs[1] << 16);
        hv.y = (unsigned)hs[2] | ((unsigned)hs[3] << 16);
        hv.z = (unsigned)hs[4] | ((unsigned)hs[5] << 16);
        hv.w = (unsigned)hs[6] | ((unsigned)hs[7] << 16);
        F[idx] = hv;
    }
}

// ---------------- prep2: k-role (z0, z0bf, H1bf) + b-role (u, ubf, U1bf) ----------------
__global__ __launch_bounds__(256) void k_prep2(
    const float* __restrict__ cb, const float* __restrict__ bc,
    const float* __restrict__ xhat,
    const float* __restrict__ WzT, const float* __restrict__ WxT,
    const float* __restrict__ W1T0,
    float* __restrict__ z0, unsigned short* __restrict__ z0bf,
    unsigned short* __restrict__ H1bf,
    float* __restrict__ u, unsigned short* __restrict__ ubf,
    unsigned short* __restrict__ U1bf)
{
    __shared__ float src[4][128];
    __shared__ float res[4][128];
    const int t = threadIdx.x;
    const bool krole = blockIdx.x < 64;
    const int r0 = (krole ? blockIdx.x : (blockIdx.x - 64)) * 4;
    const float* in = krole ? cb : xhat;
    const float* WT = krole ? WzT : WxT;
#pragma unroll
    for (int e = t; e < 512; e += 256)
        src[e >> 7][e & 127] = in[(r0 + (e >> 7)) * 128 + (e & 127)];
    __syncthreads();
    {
        const int d = t & 127, r = t >> 7;   // rows r, r+2
        float a0 = krole ? (bc[d] + src[r][d]) : 0.f;
        float a1 = krole ? (bc[d] + src[r + 2][d]) : 0.f;
        for (int j = 0; j < 128; ++j) {
            const float w = WT[j * 128 + d];
            a0 = fmaf(src[r][j], w, a0);
            a1 = fmaf(src[r + 2][j], w, a1);
        }
        float* dst = krole ? z0 : u;
        unsigned short* dstbf = krole ? z0bf : ubf;
        dst[(r0 + r) * 128 + d] = a0;        dstbf[(r0 + r) * 128 + d] = f2bh(a0);
        dst[(r0 + r + 2) * 128 + d] = a1;    dstbf[(r0 + r + 2) * 128 + d] = f2bh(a1);
        res[r][d] = a0; res[r + 2][d] = a1;
    }
    __syncthreads();
    {   // t = h: W1_0 . res  (coalesced W1T0 reads)
        float a[4] = {0.f, 0.f, 0.f, 0.f};
        for (int d = 0; d < 128; ++d) {
            const float w = W1T0[d * 256 + t];
#pragma unroll
            for (int r = 0; r < 4; ++r) a[r] = fmaf(res[r][d], w, a[r]);
        }
        if (krole) {   // frag-ordered bf16
            const int kt = t >> 4, half = (t >> 3) & 1, j = t & 7;
#pragma unroll
            for (int r = 0; r < 4; ++r) {
                int k = r0 + r; int kg = k >> 5, col = k & 31;
                H1bf[(((kg * 16 + kt) * 64) + half * 32 + col) * 8 + j] = f2bh(a[r]);
            }
        } else {
#pragma unroll
            for (int r = 0; r < 4; ++r)
                U1bf[(r0 + r) * 256 + t] = f2bh(a[r]);
        }
    }
}

// ---------------- main: approx dist + fused per-half select ----------------
// 512 thr / 8 waves; wg = (b, 128-code half q). wave: wm=wave&3, wn=wave>>2.
__global__ __launch_bounds__(512, 6) void k_dist_approx(
    const unsigned short* __restrict__ z0bf, const unsigned short* __restrict__ ubf,
    const float* __restrict__ xhat, const float* __restrict__ x,
    const uint4* __restrict__ H1u4, const unsigned short* __restrict__ U1bf,
    const uint4* __restrict__ W2f0, const uint4* __restrict__ W1f1,
    const uint4* __restrict__ W2f1,
    int* __restrict__ cand, int* __restrict__ cnt)
{
    __shared__ uint4 Zf[2048];   // 32 KB
    __shared__ uint4 Hf[1024];   // 16 KB; tail reused for red/sdist/sk

    const int t = threadIdx.x;
    const int lane = t & 63, wave = t >> 6;
    const int wm = wave & 3, wn = wave >> 2;
    const int l31 = lane & 31, l5 = lane >> 5;
    const int b = blockIdx.x >> 1, q = blockIdx.x & 1;
    const int k0 = q << 7;

    // init zs = bf(z0[k]) + bf(u[b]) at C-frag positions (d = 32wm+8rg+4l5+j)
    f32x16 zs[2];
    {
        const unsigned short* ur = ubf + b * 128;
#pragma unroll
        for (int g = 0; g < 2; ++g) {
            const int col = ((wn << 1) + g) * 32 + l31;
            const unsigned short* zr = z0bf + (k0 + col) * 128;
#pragma unroll
            for (int rg = 0; rg < 4; ++rg) {
                const int d0 = 32 * wm + 8 * rg + 4 * l5;
                ushort4 a = *(const ushort4*)(zr + d0);
                ushort4 c = *(const ushort4*)(ur + d0);
                zs[g][4*rg+0] = bh2f(a.x) + bh2f(c.x);
                zs[g][4*rg+1] = bh2f(a.y) + bh2f(c.y);
                zs[g][4*rg+2] = bh2f(a.z) + bh2f(c.z);
                zs[g][4*rg+3] = bh2f(a.w) + bh2f(c.w);
            }
        }
    }

    // P0: blk0-G2: zs += W2_0 . relu(H1pre[k]+U1[b])^T, 4 rounds of 4 kt
#pragma unroll 1
    for (int r = 0; r < 4; ++r) {
        {   // stage: wave -> kt = 4r+wm, cgs {2wn, 2wn+1}
            const int kt = 4 * r + wm;
            const uint4 uv = *(const uint4*)(U1bf + b * 256 + kt * 16 + 8 * l5);
#pragma unroll
            for (int gi = 0; gi < 2; ++gi) {
                const int cg = (wn << 1) + gi;
                const int kg = (q << 2) + cg;
                uint4 hv = H1u4[(kg * 16 + kt) * 64 + lane];
                uint4 o;
                o.x = addrelu2t(hv.x, uv.x);
                o.y = addrelu2t(hv.y, uv.y);
                o.z = addrelu2t(hv.z, uv.z);
                o.w = addrelu2t(hv.w, uv.w);
                Hf[((cg << 2) + wm) * 64 + lane] = o;
            }
        }
        __syncthreads();
#pragma unroll
        for (int ktl = 0; ktl < 4; ++ktl) {
            uint4 ah = W2f0[((wm << 4) + 4 * r + ktl) * 64 + lane];
#pragma unroll
            for (int g = 0; g < 2; ++g) {
                uint4 bv = Hf[((((wn << 1) + g) << 2) + ktl) * 64 + lane];
                zs[g] = mfma_bf(ah, bv, zs[g]);
            }
        }
        __syncthreads();
    }

    // P1: write z1 (trunc bf16) to Zf in B-frag order
#pragma unroll
    for (int g = 0; g < 2; ++g) {
        const int cg = (wn << 1) + g;
#pragma unroll
        for (int rg = 0; rg < 4; ++rg) {
            uint2 hv;
            hv.x = packhi(zs[g][4*rg+0], zs[g][4*rg+1]);
            hv.y = packhi(zs[g][4*rg+2], zs[g][4*rg+3]);
            uint2* zb2 = (uint2*)&Zf[((cg << 3) + 2 * wm + (rg >> 1)) * 64];
            zb2[(((rg & 1) << 5) + l31) * 2 + l5] = hv;
        }
    }
    __syncthreads();

    // P2: blk1, 4 chunks of 64 h. G1: wave -> tile = wave&1, cg = wave>>1.
    const int tile = wave & 1, cg1 = wave >> 1;
#pragma unroll 1
    for (int c = 0; c < 4; ++c) {
        f32x16 acc;
#pragma unroll
        for (int rr = 0; rr < 16; ++rr) acc[rr] = 0.f;
        {
            const uint4* pw1 = W1f1 + ((2 * c + tile) << 3) * 64;
#pragma unroll
            for (int kt = 0; kt < 8; ++kt) {
                uint4 bv = Zf[((cg1 << 3) + kt) * 64 + lane];
                uint4 ah = pw1[kt * 64 + lane];
                acc = mfma_bf(ah, bv, acc);
            }
        }
        __syncthreads();   // previous chunk's Hf readers done
#pragma unroll
        for (int rg = 0; rg < 4; ++rg) {
            float v0 = fmaxf(acc[4*rg+0], 0.f), v1 = fmaxf(acc[4*rg+1], 0.f);
            float v2 = fmaxf(acc[4*rg+2], 0.f), v3 = fmaxf(acc[4*rg+3], 0.f);
            uint2 hv; hv.x = packhi(v0, v1); hv.y = packhi(v2, v3);
            uint2* hb2 = (uint2*)&Hf[((cg1 << 2) + (tile << 1) + (rg >> 1)) * 64];
            hb2[(((rg & 1) << 5) + l31) * 2 + l5] = hv;
        }
        __syncthreads();
#pragma unroll
        for (int ktl = 0; ktl < 4; ++ktl) {
            uint4 ah = W2f1[((wm << 4) + 4 * c + ktl) * 64 + lane];
#pragma unroll
            for (int g = 0; g < 2; ++g) {
                uint4 bv = Hf[((((wn << 1) + g) << 2) + ktl) * 64 + lane];
                zs[g] = mfma_bf(ah, bv, zs[g]);
            }
        }
    }

    // P3: dist + per-half candidate selection (fixed slots, no atomics)
    float* red   = (float*)Hf;          // [4][128]
    float* sdist = (float*)Hf + 512;    // [128]
    int*   sk    = (int*)((float*)Hf + 640);   // [8]
    __syncthreads();
#pragma unroll
    for (int g = 0; g < 2; ++g) {
        float s = 0.f;
        const int col = ((wn << 1) + g) * 32 + l31;
#pragma unroll
        for (int rg = 0; rg < 4; ++rg) {
            const int d0 = 32 * wm + 8 * rg + 4 * l5;
            float4 xh = *(const float4*)(xhat + b * 128 + d0);
            float4 xx = *(const float4*)(x + b * 128 + d0);
            float v;
            v = zs[g][4*rg+0] + xh.x - xx.x; s = fmaf(v, v, s);
            v = zs[g][4*rg+1] + xh.y - xx.y; s = fmaf(v, v, s);
            v = zs[g][4*rg+2] + xh.z - xx.z; s = fmaf(v, v, s);
            v = zs[g][4*rg+3] + xh.w - xx.w; s = fmaf(v, v, s);
        }
        s += __shfl_xor(s, 32, 64);
        if (l5 == 0) red[wm * 128 + col] = s;
    }
    __syncthreads();
    if (t < 128)
        sdist[t] = red[t] + red[128 + t] + red[256 + t] + red[384 + t];
    __syncthreads();
    if (wave == 0) {
        int base = 0;
        float v0 = sdist[lane], v1 = sdist[lane + 64];
        float m = fminf(v0, v1);
#pragma unroll
        for (int off = 32; off > 0; off >>= 1) m = fminf(m, __shfl_xor(m, off, 64));
        const float thr = m + DELTA;
        const unsigned long long below = (1ull << lane) - 1;
        float vv[2] = {v0, v1};
#pragma unroll
        for (int j = 0; j < 2; ++j) {
            bool p = vv[j] <= thr;
            unsigned long long mask = __ballot(p);
            int pos = base + __popcll(mask & below);
            if (p && pos < 8) sk[pos] = k0 + 64 * j + lane;   // k-ascending order
            base += __popcll(mask);
        }
        if (lane == 0) {
            int c = base > 8 ? 8 : base;
            cnt[b * 2 + q] = c;
            for (int s2 = 0; s2 < c; ++s2)
                cand[(b * 2 + q) * 8 + s2] = sk[s2];
        }
    }
}

// ---------------- final: per-b exact f32 recompute of <=16 cands + pick + output ----------------
__global__ __launch_bounds__(256) void k_final2(
    const float* __restrict__ z0, const float* __restrict__ u,
    const float* __restrict__ xhat, const float* __restrict__ x,
    const int* __restrict__ cand, const int* __restrict__ cnt,
    const float* __restrict__ W1Ta, const float* __restrict__ W2Ta,
    const float* __restrict__ W1Tb, const float* __restrict__ W2Tb,
    float* __restrict__ out0, float* __restrict__ outd)
{
    __shared__ float z16[16][128];
    __shared__ float h8[8][256];
    __shared__ int ck[16];
    __shared__ float dd[16];
    __shared__ int widx;
    const int t = threadIdx.x, b = blockIdx.x;
    const int c0 = cnt[2 * b], c1 = cnt[2 * b + 1];
    const int tot = c0 + c1;   // 2..16 (>=1 per half)
    if (t < 16) {
        int k;
        if (t < c0)          k = cand[2 * b * 8 + t];
        else if (t < tot)    k = cand[(2 * b + 1) * 8 + (t - c0)];
        else                 k = cand[2 * b * 8];     // pad: replicate slot 0
        ck[t] = k;
    }
    __syncthreads();
    const int nb = (tot > 8) ? 2 : 1;
#pragma unroll 1
    for (int batch = 0; batch < nb; ++batch) {
        const int bo = batch * 8;
        const float* ub = u + b * 128;
#pragma unroll
        for (int n = 0; n < 4; ++n) {
            int e = n * 256 + t; int r = e >> 7, d = e & 127;
            z16[bo + r][d] = z0[ck[bo + r] * 128 + d] + ub[d];
        }
        __syncthreads();
        const float* W1T = W1Ta; const float* W2T = W2Ta;
#pragma unroll 1
        for (int blk = 0; blk < 2; ++blk) {
            float a1[8] = {0.f,0.f,0.f,0.f,0.f,0.f,0.f,0.f};
            for (int d = 0; d < 128; ++d) {
                const float w = W1T[d * 256 + t];
#pragma unroll
                for (int r = 0; r < 8; ++r) a1[r] = fmaf(z16[bo + r][d], w, a1[r]);
            }
#pragma unroll
            for (int r = 0; r < 8; ++r) h8[r][t] = fmaxf(a1[r], 0.f);
            __syncthreads();
            const int ig = t & 127, rg = (t >> 7) * 4;
            float a2[4] = {0.f,0.f,0.f,0.f};
            for (int h = 0; h < 256; ++h) {
                const float w = W2T[h * 128 + ig];
#pragma unroll
                for (int j = 0; j < 4; ++j) a2[j] = fmaf(h8[rg + j][h], w, a2[j]);
            }
            __syncthreads();
#pragma unroll
            for (int j = 0; j < 4; ++j) z16[bo + rg + j][ig] += a2[j];
            __syncthreads();
            W1T = W1Tb; W2T = W2Tb;
        }
        {   // exact dist for this batch (part overlays h8 — free after sync above)
            float* part = (float*)h8;
            const int r = t >> 5, c = t & 31;
            float s = 0.f;
#pragma unroll
            for (int i = 0; i < 4; ++i) {
                int d = c * 4 + i;
                float v = z16[bo + r][d] + xhat[b * 128 + d] - x[b * 128 + d];
                s = fmaf(v, v, s);
            }
            part[r * 32 + c] = s;
            __syncthreads();
            if (t < 8) {
                float ssum = 0.f;
#pragma unroll
                for (int c2 = 0; c2 < 32; ++c2) ssum += part[t * 32 + c2];
                dd[bo + t] = ssum;
            }
            __syncthreads();
        }
    }
    if (t == 0) {   // slots are k-ascending -> strict < keeps lowest k on ties
        float bv = dd[0]; int w = 0;
        for (int s = 1; s < tot; ++s)
            if (dd[s] < bv) { bv = dd[s]; w = s; }
        widx = w;
        out0[b] = (float)ck[w];
    }
    __syncthreads();
    if (t < 128) outd[b * 128 + t] = z16[widx][t];
}

extern "C" void kernel_launch(void* const* d_in, const int* in_sizes, int n_in,
                              void* d_out, int out_size, void* d_ws, size_t ws_size,
                              hipStream_t stream) {
    const float* xhat = (const float*)d_in[0];
    const float* x    = (const float*)d_in[1];
    const float* cb   = (const float*)d_in[2];
    const float* Wc   = (const float*)d_in[3];
    const float* bc   = (const float*)d_in[4];
    const float* W1_0 = (const float*)d_in[5];
    const float* W2_0 = (const float*)d_in[6];
    const float* W1_1 = (const float*)d_in[7];
    const float* W2_1 = (const float*)d_in[8];
    float* out = (float*)d_out;
    float* ws  = (float*)d_ws;

    float* WzT   = ws + 0;
    float* WxT   = ws + 16384;
    float* W1T0  = ws + 32768;
    float* W2T0  = ws + 65536;
    float* W1T1  = ws + 98304;
    float* W2T1  = ws + 131072;
    float* z0    = ws + 163840;
    float* u     = ws + 196608;
    unsigned short* z0bf = (unsigned short*)(ws + 458752);
    unsigned short* ubf  = (unsigned short*)(ws + 475136);
    unsigned short* U1bf = (unsigned short*)(ws + 606208);
    unsigned short* H1bf = (unsigned short*)(ws + 868352);   // 32768 floats worth
    uint4* F     = (uint4*)(ws + 901120);                    // moved past H1bf
    const uint4* W2f0 = F;
    const uint4* W1f1 = F + 4096;
    const uint4* W2f1 = F + 8192;
    int* cand = (int*)(ws + 950272);
    int* cnt  = (int*)(ws + 983040);

    k_prep1<<<688, 256, 0, stream>>>(Wc, W1_0, W2_0, W1_1, W2_1,
                                     WzT, WxT, W1T0, W2T0, W1T1, W2T1, F);
    k_prep2<<<576, 256, 0, stream>>>(cb, bc, xhat, WzT, WxT, W1T0,
                                     z0, z0bf, H1bf, u, ubf, U1bf);
    k_dist_approx<<<4096, 512, 0, stream>>>(z0bf, ubf, xhat, x, (const uint4*)H1bf,
                                            U1bf, W2f0, W1f1, W2f1, cand, cnt);
    k_final2<<<2048, 256, 0, stream>>>(z0, u, xhat, x, cand, cnt,
                                       W1T0, W2T0, W1T1, W2T1, out, out + 2048);
}